// Round 6
// baseline (224.880 us; speedup 1.0000x reference)
//
#include <hip/hip_runtime.h>
#include <hip/hip_bf16.h>

// Problem constants
constexpr int B_   = 8;
constexpr int D_   = 1024;
constexpr int T_   = 512;
constexpr int HID_ = 256;
constexpr int NH_  = 4;
constexpr int NL_  = 2;
constexpr float ALPHA_ = 0.2f;
constexpr float EPS_   = 1e-5f;
constexpr int OUT_ = 64;
constexpr int M_ = B_ * D_;      // 8192 rows
constexpr int DT_ = D_ * T_;     // 524288
constexpr int KIN_ = 2 * T_;     // 1024

typedef __attribute__((ext_vector_type(8))) short short8;   // 8 bf16 (4 VGPRs)
typedef __attribute__((ext_vector_type(4))) float floatx4;  // 4 fp32 acc

__device__ __forceinline__ unsigned short f2bf(float f) {
    unsigned int u = __float_as_uint(f);
    unsigned int r = u + 0x7fffu + ((u >> 16) & 1u);   // round-to-nearest-even
    return (unsigned short)(r >> 16);
}
__device__ __forceinline__ float bf2f(unsigned short u) {
    return __uint_as_float((unsigned int)u << 16);
}
// monotone float<->uint key for atomicMax on signed floats
__device__ __forceinline__ unsigned int kenc(float f) {
    unsigned int u = __float_as_uint(f);
    return (u & 0x80000000u) ? ~u : (u | 0x80000000u);
}
__device__ __forceinline__ float kdec(unsigned int k) {
    unsigned int u = (k & 0x80000000u) ? (k ^ 0x80000000u) : ~k;
    return __uint_as_float(u);
}
// async global->LDS, 16 bytes per lane (wave-uniform LDS base + lane*16)
__device__ __forceinline__ void gll16(const unsigned short* g, unsigned short* l) {
    __builtin_amdgcn_global_load_lds(
        (const __attribute__((address_space(1))) void*)g,
        (__attribute__((address_space(3))) void*)l, 16, 0, 0);
}

// ---------------------------------------------------------------------------
// 1) Imputation -> packed bf16 concat matrix A_in[M][1024] = [X_mean | mask]
// ---------------------------------------------------------------------------
__global__ __launch_bounds__(256) void impute_k(const float* __restrict__ X,
                                                const float* __restrict__ Mk,
                                                unsigned short* __restrict__ Ain) {
    int idx4 = (blockIdx.x * 256 + threadIdx.x) * 4;   // over D*T
    int t = idx4 & (T_ - 1);
    int d = idx4 >> 9;
    float4 x[B_], m[B_];
    float4 s = {0, 0, 0, 0}, c = {0, 0, 0, 0};
#pragma unroll
    for (int b = 0; b < B_; b++) {
        x[b] = *(const float4*)&X[(size_t)b * DT_ + idx4];
        m[b] = *(const float4*)&Mk[(size_t)b * DT_ + idx4];
        s.x += x[b].x * m[b].x; s.y += x[b].y * m[b].y;
        s.z += x[b].z * m[b].z; s.w += x[b].w * m[b].w;
        c.x += m[b].x; c.y += m[b].y; c.z += m[b].z; c.w += m[b].w;
    }
    float4 pm;
    pm.x = s.x / (c.x + 1e-10f); pm.y = s.y / (c.y + 1e-10f);
    pm.z = s.z / (c.z + 1e-10f); pm.w = s.w / (c.w + 1e-10f);
#pragma unroll
    for (int b = 0; b < B_; b++) {
        size_t row = (size_t)b * D_ + d;
        ushort4 xm, mk;
        xm.x = f2bf(x[b].x * m[b].x + (1.f - m[b].x) * pm.x);
        xm.y = f2bf(x[b].y * m[b].y + (1.f - m[b].y) * pm.y);
        xm.z = f2bf(x[b].z * m[b].z + (1.f - m[b].z) * pm.z);
        xm.w = f2bf(x[b].w * m[b].w + (1.f - m[b].w) * pm.w);
        mk.x = f2bf(m[b].x); mk.y = f2bf(m[b].y);
        mk.z = f2bf(m[b].z); mk.w = f2bf(m[b].w);
        *(ushort4*)&Ain[row * KIN_ + t]      = xm;
        *(ushort4*)&Ain[row * KIN_ + T_ + t] = mk;
    }
}

// ---------------------------------------------------------------------------
// 2) Fused weight prep: Wt_in (bf16 [256][1024]), Wcat (bf16 [l][256][256]),
//    WtO (bf16 [512][256]), rmaxkey init. 2048 blocks x 256.
// ---------------------------------------------------------------------------
__global__ __launch_bounds__(256) void wprep_k(const float* __restrict__ W_in,
                                               const float* __restrict__ gatW,
                                               const float* __restrict__ W_out,
                                               unsigned short* __restrict__ Wt_in,
                                               unsigned short* __restrict__ Wcat,
                                               unsigned short* __restrict__ WtO,
                                               unsigned int* __restrict__ rmaxkey) {
    int idx = blockIdx.x * 256 + threadIdx.x;
    if (idx < 64) rmaxkey[idx] = 0u;           // per (l,bh) max-key init
    if (idx < 262144) {
        int n = idx >> 10, k = idx & 1023;     // Wt_in[n][k] = W_in[k][n]
        Wt_in[idx] = f2bf(W_in[(size_t)k * HID_ + n]);
    } else if (idx < 393216) {
        int j = idx - 262144;
        int l = j >> 16, n = (j >> 8) & 255, k = j & 255;
        int h = n >> 6, e = n & 63;
        Wcat[j] = f2bf(gatW[(((size_t)(l * NH_ + h) * HID_) + k) * OUT_ + e]);
    } else {
        int j = idx - 393216;
        int n = j >> 8, k = j & 255;           // WtO[n][k] = W_out[k][n]
        WtO[j] = f2bf(W_out[(size_t)k * T_ + n]);
    }
}

// ---------------------------------------------------------------------------
// 3) bf16 MFMA GEMM, global_load_lds(16B) + ping-pong LDS, 1 barrier/iter.
//    C = A[M,K] @ Bt[N,K]^T. BM=128 BN=64 BK=32, 4 waves.
//    MODE 0: fp32 C (+bias). MODE 1: fp32 C + bf16 copy (+bias).
//    MODE 2: per-head transposed bf16 -> hwT[bh][e][m], fused s_l/s_r/rmax.
// ---------------------------------------------------------------------------
template <int MODE>
__global__ __launch_bounds__(256) void gemm_bf16_k(
        const unsigned short* __restrict__ A,    // M x K bf16
        const unsigned short* __restrict__ Bt,   // N x K bf16 (B transposed)
        const float* __restrict__ bias,          // N or null (MODE 0/1)
        float* __restrict__ C,                   // M x N fp32 (MODE 0/1)
        unsigned short* __restrict__ Cb,         // bf16 copy (MODE1) / hwT (MODE2)
        const float* __restrict__ ga,            // gat_a + l*512 (MODE2)
        float* __restrict__ s_l,                 // (MODE2)
        float* __restrict__ s_r,                 // (MODE2)
        unsigned int* __restrict__ rmaxkey,      // + l*32 (MODE2)
        int Nsz, int Ksz) {
    __shared__ __align__(16) unsigned short As[2][128 * 32];  // 16 KB
    __shared__ __align__(16) unsigned short Bs[2][64 * 32];   // 8 KB
    int tid = threadIdx.x;
    int wave = tid >> 6, lane = tid & 63;
    int q = lane >> 4, r16 = lane & 15;
    int rowbase = blockIdx.y * 128;
    int colbase = blockIdx.x * 64;

    const unsigned short* Ap0 = A + (size_t)(rowbase + (tid >> 2)) * Ksz + (tid & 3) * 8;
    const unsigned short* Ap1 = A + (size_t)(rowbase + (tid >> 2) + 64) * Ksz + (tid & 3) * 8;
    const unsigned short* Bp  = Bt + (size_t)(colbase + (tid >> 2)) * Ksz + (tid & 3) * 8;

    floatx4 acc[2][4];
#pragma unroll
    for (int i = 0; i < 2; i++)
#pragma unroll
        for (int j = 0; j < 4; j++) acc[i][j] = (floatx4)0.f;

    // prologue: async-stage K-tile 0 into buffer 0
    gll16(Ap0, &As[0][tid * 8]);
    gll16(Ap1, &As[0][(tid + 256) * 8]);
    gll16(Bp,  &Bs[0][tid * 8]);

    int nk = Ksz >> 5;
    for (int it = 0; it < nk; it++) {
        int cur = it & 1;
        __syncthreads();   // drains vmcnt -> buf[cur] ready; buf[cur^1] readers done
        if (it + 1 < nk) {
            int kt2 = (it + 1) << 5;
            gll16(Ap0 + kt2, &As[cur ^ 1][tid * 8]);
            gll16(Ap1 + kt2, &As[cur ^ 1][(tid + 256) * 8]);
            gll16(Bp + kt2,  &Bs[cur ^ 1][tid * 8]);
        }
        short8 a[2], b[4];
#pragma unroll
        for (int mi = 0; mi < 2; mi++)
            a[mi] = *(const short8*)&As[cur][(wave * 32 + mi * 16 + r16) * 32 + q * 8];
#pragma unroll
        for (int ni = 0; ni < 4; ni++)
            b[ni] = *(const short8*)&Bs[cur][(ni * 16 + r16) * 32 + q * 8];
#pragma unroll
        for (int mi = 0; mi < 2; mi++)
#pragma unroll
            for (int ni = 0; ni < 4; ni++)
                acc[mi][ni] = __builtin_amdgcn_mfma_f32_16x16x32_bf16(
                    a[mi], b[ni], acc[mi][ni], 0, 0, 0);
    }
    // ---- epilogue. C/D map: col=lane&15, row=(lane>>4)*4+reg ----
    if constexpr (MODE == 2) {
        int bhh = ((rowbase >> 10) << 2) + blockIdx.x;   // b*4 + h
        int nbase = (rowbase & (D_ - 1)) + wave * 32;
        // hwT[bh][e][m] bf16
#pragma unroll
        for (int mi = 0; mi < 2; mi++) {
#pragma unroll
            for (int ni = 0; ni < 4; ni++) {
                int e = ni * 16 + r16;
                ushort4 pk;
                pk.x = f2bf(acc[mi][ni][0]);
                pk.y = f2bf(acc[mi][ni][1]);
                pk.z = f2bf(acc[mi][ni][2]);
                pk.w = f2bf(acc[mi][ni][3]);
                *(ushort4*)&Cb[((size_t)(bhh * 64 + e) << 10) + nbase + mi * 16 + q * 4] = pk;
            }
        }
        // fused s_l / s_r from fp32 acc: reduce over e (ni regs + r16 lanes)
        const float* gab = ga + blockIdx.x * 2 * OUT_;
        float al4[4], ar4[4];
#pragma unroll
        for (int ni = 0; ni < 4; ni++) {
            al4[ni] = gab[ni * 16 + r16];
            ar4[ni] = gab[OUT_ + ni * 16 + r16];
        }
        float slv[2][4], srv[2][4];
#pragma unroll
        for (int mi = 0; mi < 2; mi++)
#pragma unroll
            for (int rr = 0; rr < 4; rr++) {
                float s1 = 0.f, s2 = 0.f;
#pragma unroll
                for (int ni = 0; ni < 4; ni++) {
                    s1 += acc[mi][ni][rr] * al4[ni];
                    s2 += acc[mi][ni][rr] * ar4[ni];
                }
                slv[mi][rr] = s1;
                srv[mi][rr] = s2;
            }
#pragma unroll
        for (int off = 1; off < 16; off <<= 1) {
#pragma unroll
            for (int mi = 0; mi < 2; mi++)
#pragma unroll
                for (int rr = 0; rr < 4; rr++) {
                    slv[mi][rr] += __shfl_xor(slv[mi][rr], off, 64);
                    srv[mi][rr] += __shfl_xor(srv[mi][rr], off, 64);
                }
        }
        // writers: r16 0..7 -> s_l slots, 8..15 -> s_r slots
        {
            int slot = r16 & 7;
            int mi = slot >> 2, rr = slot & 3;
            int n = nbase + mi * 16 + q * 4 + rr;
            if (r16 < 8) s_l[bhh * D_ + n] = slv[mi][rr];
            else         s_r[bhh * D_ + n] = srv[mi][rr];
        }
        // per-(l,bh) running max of s_r
        float mx = -1e30f;
#pragma unroll
        for (int mi = 0; mi < 2; mi++)
#pragma unroll
            for (int rr = 0; rr < 4; rr++) mx = fmaxf(mx, srv[mi][rr]);
        if (lane == 0) atomicMax(&rmaxkey[bhh], kenc(mx));
    } else {
#pragma unroll
        for (int mi = 0; mi < 2; mi++) {
#pragma unroll
            for (int rr = 0; rr < 4; rr++) {
                int row = rowbase + wave * 32 + mi * 16 + q * 4 + rr;
#pragma unroll
                for (int ni = 0; ni < 4; ni++) {
                    int col = colbase + ni * 16 + r16;
                    float v = acc[mi][ni][rr] + (bias ? bias[col] : 0.f);
                    C[(size_t)row * Nsz + col] = v;
                    if constexpr (MODE == 1) Cb[(size_t)row * Nsz + col] = f2bf(v);
                }
            }
        }
    }
}

// ---------------------------------------------------------------------------
// 5) Attention via MFMA, double-buffered V staging. grid (32 bh, 16 rowblocks
//    of 64), 256 thr, 4 waves. Wave = one 16-row tile; P (bf16) in registers.
// ---------------------------------------------------------------------------
__global__ __launch_bounds__(256) void attn_k(const unsigned short* __restrict__ hwT,
                                              const float* __restrict__ sl_g,
                                              const float* __restrict__ sr_g,
                                              const unsigned int* __restrict__ rmaxkey,
                                              float* __restrict__ hnew) {
    int bh = blockIdx.x;
    int b = bh >> 2, h = bh & 3;
    int tid = threadIdx.x;
    int wave = tid >> 6, lane = tid & 63;
    int q = lane >> 4, r16 = lane & 15;

    __shared__ float srs[D_];                                 // 4 KB
    __shared__ __align__(16) unsigned short Vt[2][64][136];   // 34.8 KB ping-pong
    __shared__ float den_lds[64];

    *(float4*)&srs[tid * 4] = *(const float4*)&sr_g[bh * D_ + tid * 4];

    float rm = kdec(rmaxkey[bh]);
    int row0 = blockIdx.y * 64 + wave * 16;
    float sl = sl_g[bh * D_ + row0 + r16];
    float xm = sl + rm;
    float Mn = fmaxf(xm, ALPHA_ * xm);

    floatx4 acc[4];
#pragma unroll
    for (int i = 0; i < 4; i++) acc[i] = (floatx4)0.f;
    float dsum = 0.f;

    const unsigned short* vbase = hwT + ((size_t)(bh * 64) << 10);
    int se[4], sp[4];
#pragma unroll
    for (int i = 0; i < 4; i++) {
        int s = tid + i * 256;
        se[i] = s >> 4;
        sp[i] = (s & 15) * 8;
    }

    // prologue: stage chunk 0 into buffer 0
    uint4 pre[4];
#pragma unroll
    for (int i = 0; i < 4; i++)
        pre[i] = *(const uint4*)&vbase[((size_t)se[i] << 10) + sp[i]];
#pragma unroll
    for (int i = 0; i < 4; i++)
        *(uint4*)&Vt[0][se[i]][sp[i]] = pre[i];
    __syncthreads();   // buffer 0 + srs ready

    for (int c = 0; c < 8; c++) {
        int cur = c & 1;
        // issue next chunk's global loads (in flight across compute)
        if (c < 7) {
            int mc = (c + 1) * 128;
#pragma unroll
            for (int i = 0; i < 4; i++)
                pre[i] = *(const uint4*)&vbase[((size_t)se[i] << 10) + mc + sp[i]];
        }
#pragma unroll
        for (int kk = 0; kk < 128; kk += 32) {
            int m0 = c * 128 + kk + q * 8;
            float4 s0 = *(const float4*)&srs[m0];
            float4 s1 = *(const float4*)&srs[m0 + 4];
            float sr8[8] = {s0.x, s0.y, s0.z, s0.w, s1.x, s1.y, s1.z, s1.w};
            float p[8];
#pragma unroll
            for (int j = 0; j < 8; j++) {
                float x = sl + sr8[j];
                float e = fmaxf(x, ALPHA_ * x);
                float pj = __expf(e - Mn);
                dsum += pj;
                p[j] = pj;
            }
            union { unsigned int u[4]; short8 s8; } cv;
#pragma unroll
            for (int j = 0; j < 4; j++) {
                unsigned int lo = (__float_as_uint(p[2 * j]) + 0x8000u) >> 16;
                unsigned int hi = (__float_as_uint(p[2 * j + 1]) + 0x8000u) & 0xffff0000u;
                cv.u[j] = hi | lo;
            }
#pragma unroll
            for (int ni = 0; ni < 4; ni++) {
                short8 bfr = *(const short8*)&Vt[cur][ni * 16 + r16][kk + q * 8];
                acc[ni] = __builtin_amdgcn_mfma_f32_16x16x32_bf16(cv.s8, bfr, acc[ni], 0, 0, 0);
            }
        }
        if (c < 7) {
#pragma unroll
            for (int i = 0; i < 4; i++)
                *(uint4*)&Vt[cur ^ 1][se[i]][sp[i]] = pre[i];
        }
        __syncthreads();
    }
    dsum += __shfl_xor(dsum, 16);
    dsum += __shfl_xor(dsum, 32);
    if (q == 0) den_lds[wave * 16 + r16] = dsum;
    __syncthreads();
#pragma unroll
    for (int rr = 0; rr < 4; rr++) {
        int rloc = q * 4 + rr;
        float rden = 1.f / den_lds[wave * 16 + rloc];
        size_t grow = (size_t)(b * D_ + blockIdx.y * 64 + wave * 16 + rloc);
#pragma unroll
        for (int ni = 0; ni < 4; ni++) {
            hnew[grow * HID_ + h * OUT_ + ni * 16 + r16] = acc[ni][rr] * rden;
        }
    }
}

// ---------------------------------------------------------------------------
// 6) h = LayerNorm(h + hnew)*g + b. One wave per row, shfl-only reductions.
// ---------------------------------------------------------------------------
__global__ __launch_bounds__(256) void addln_k(float* __restrict__ h,
                                               const float* __restrict__ hn,
                                               const float* __restrict__ g,
                                               const float* __restrict__ bb,
                                               unsigned short* __restrict__ hbf) {
    int wave = threadIdx.x >> 6, lane = threadIdx.x & 63;
    size_t row = (size_t)blockIdx.x * 4 + wave;
    float4 a = *(const float4*)&h[row * HID_ + lane * 4];
    float4 r = *(const float4*)&hn[row * HID_ + lane * 4];
    float4 v = {a.x + r.x, a.y + r.y, a.z + r.z, a.w + r.w};
    float s = v.x + v.y + v.z + v.w;
#pragma unroll
    for (int off = 1; off < 64; off <<= 1) s += __shfl_xor(s, off, 64);
    float mu = s * (1.f / HID_);
    float4 d = {v.x - mu, v.y - mu, v.z - mu, v.w - mu};
    float s2 = d.x * d.x + d.y * d.y + d.z * d.z + d.w * d.w;
#pragma unroll
    for (int off = 1; off < 64; off <<= 1) s2 += __shfl_xor(s2, off, 64);
    float rs = rsqrtf(s2 * (1.f / HID_) + EPS_);
    float4 gg = *(const float4*)&g[lane * 4];
    float4 bbv = *(const float4*)&bb[lane * 4];
    float4 res;
    res.x = d.x * rs * gg.x + bbv.x;
    res.y = d.y * rs * gg.y + bbv.y;
    res.z = d.z * rs * gg.z + bbv.z;
    res.w = d.w * rs * gg.w + bbv.w;
    *(float4*)&h[row * HID_ + lane * 4] = res;
    ushort4 pk = {f2bf(res.x), f2bf(res.y), f2bf(res.z), f2bf(res.w)};
    *(ushort4*)&hbf[row * HID_ + lane * 4] = pk;
}

// ---------------------------------------------------------------------------
extern "C" void kernel_launch(void* const* d_in, const int* in_sizes, int n_in,
                              void* d_out, int out_size, void* d_ws, size_t ws_size,
                              hipStream_t stream) {
    const float* X_obs = (const float*)d_in[0];
    const float* mask  = (const float*)d_in[1];
    const float* W_in  = (const float*)d_in[2];
    const float* b_in  = (const float*)d_in[3];
    const float* gat_W = (const float*)d_in[4];
    const float* gat_a = (const float*)d_in[5];
    const float* ln_g  = (const float*)d_in[6];
    const float* ln_b  = (const float*)d_in[7];
    const float* W_out = (const float*)d_in[8];
    const float* b_out = (const float*)d_in[9];
    float* out = (float*)d_out;

    // Workspace (~29.3 MB):
    //  [0,16M):  Ain bf16 (M x 1024); dead after concat GEMM, reused as
    //            hwT bf16 (4 MB) at 0, hnew fp32 (8 MB) at 4M..12M
    //  [16,24M): hbuf fp32 (M x 256)
    //  [24,28M): hbf bf16 (M x 256)
    //  [28M...): Wt_in, Wcat, WtO (bf16), slb/srb (fp32), rmaxkey (uint[64])
    char* base = (char*)d_ws;
    unsigned short* Ain  = (unsigned short*)base;
    unsigned short* hwT  = (unsigned short*)base;
    float* hnew = (float*)(base + (4u << 20));
    float* hbuf = (float*)(base + (16u << 20));
    unsigned short* hbf   = (unsigned short*)(base + (24u << 20));
    unsigned short* Wt_in = (unsigned short*)(base + (28u << 20));
    unsigned short* Wcat  = Wt_in + (size_t)HID_ * KIN_;        // 256*1024
    unsigned short* WtO   = Wcat + (size_t)NL_ * HID_ * HID_;   // 2*256*256
    float* slb = (float*)(WtO + (size_t)T_ * HID_);             // 32*1024
    float* srb = slb + B_ * NH_ * D_;
    unsigned int* rmaxkey = (unsigned int*)(srb + B_ * NH_ * D_);  // [2][32]

    impute_k<<<DT_ / 1024, 256, 0, stream>>>(X_obs, mask, Ain);
    wprep_k<<<2048, 256, 0, stream>>>(W_in, gat_W, W_out, Wt_in, Wcat, WtO, rmaxkey);

    // h = [X_mean|mask] @ W_in + b_in   (8192x1024)@(1024x256), fp32+bf16 out
    gemm_bf16_k<1><<<dim3(HID_ / 64, M_ / 128), 256, 0, stream>>>(
        Ain, Wt_in, b_in, hbuf, hbf, nullptr, nullptr, nullptr, nullptr,
        HID_, KIN_);

    for (int l = 0; l < NL_; l++) {
        // hW = h @ Wcat[l] -> hwT bf16 + fused s_l/s_r/rmax
        gemm_bf16_k<2><<<dim3(HID_ / 64, M_ / 128), 256, 0, stream>>>(
            hbf, Wcat + (size_t)l * HID_ * HID_, nullptr, nullptr, hwT,
            gat_a + (size_t)l * NH_ * 2 * OUT_, slb, srb, rmaxkey + l * 32,
            HID_, HID_);
        attn_k<<<dim3(B_ * NH_, D_ / 64), 256, 0, stream>>>(
            hwT, slb, srb, rmaxkey + l * 32, hnew);
        addln_k<<<M_ / 4, 256, 0, stream>>>(hbuf, hnew, ln_g + (size_t)l * HID_,
                                            ln_b + (size_t)l * HID_, hbf);
    }

    // out = h @ W_out + b_out  (8192x256)@(256x512), fp32 out
    gemm_bf16_k<0><<<dim3(T_ / 64, M_ / 128), 256, 0, stream>>>(
        hbf, WtO, b_out, out, nullptr, nullptr, nullptr, nullptr, nullptr,
        T_, HID_);
}

// Round 7
// 216.524 us; speedup vs baseline: 1.0386x; 1.0386x over previous
//
#include <hip/hip_runtime.h>
#include <hip/hip_bf16.h>

// Problem constants
constexpr int B_   = 8;
constexpr int D_   = 1024;
constexpr int T_   = 512;
constexpr int HID_ = 256;
constexpr int NH_  = 4;
constexpr int NL_  = 2;
constexpr float ALPHA_ = 0.2f;
constexpr float EPS_   = 1e-5f;
constexpr int OUT_ = 64;
constexpr int M_ = B_ * D_;      // 8192 rows
constexpr int DT_ = D_ * T_;     // 524288
constexpr int KIN_ = 2 * T_;     // 1024

typedef __attribute__((ext_vector_type(8))) short short8;   // 8 bf16 (4 VGPRs)
typedef __attribute__((ext_vector_type(4))) float floatx4;  // 4 fp32 acc

__device__ __forceinline__ unsigned short f2bf(float f) {
    unsigned int u = __float_as_uint(f);
    unsigned int r = u + 0x7fffu + ((u >> 16) & 1u);   // round-to-nearest-even
    return (unsigned short)(r >> 16);
}
// monotone float<->uint key for atomicMax on signed floats
__device__ __forceinline__ unsigned int kenc(float f) {
    unsigned int u = __float_as_uint(f);
    return (u & 0x80000000u) ? ~u : (u | 0x80000000u);
}
__device__ __forceinline__ float kdec(unsigned int k) {
    unsigned int u = (k & 0x80000000u) ? (k ^ 0x80000000u) : ~k;
    return __uint_as_float(u);
}

// ---------------------------------------------------------------------------
// 1) Fused prep: blocks [0,512): imputation -> Ain bf16 [M][1024]=[X_mean|mask]
//    blocks [512,2560): weight transpose/convert + rmaxkey init
// ---------------------------------------------------------------------------
__global__ __launch_bounds__(256) void prep_k(const float* __restrict__ X,
                                              const float* __restrict__ Mk,
                                              const float* __restrict__ W_in,
                                              const float* __restrict__ gatW,
                                              const float* __restrict__ W_out,
                                              unsigned short* __restrict__ Ain,
                                              unsigned short* __restrict__ Wt_in,
                                              unsigned short* __restrict__ Wcat,
                                              unsigned short* __restrict__ WtO,
                                              unsigned int* __restrict__ rmaxkey) {
    int bx = blockIdx.x;
    if (bx < 512) {
        int idx4 = (bx * 256 + threadIdx.x) * 4;   // over D*T
        int t = idx4 & (T_ - 1);
        int d = idx4 >> 9;
        float4 x[B_], m[B_];
        float4 s = {0, 0, 0, 0}, c = {0, 0, 0, 0};
#pragma unroll
        for (int b = 0; b < B_; b++) {
            x[b] = *(const float4*)&X[(size_t)b * DT_ + idx4];
            m[b] = *(const float4*)&Mk[(size_t)b * DT_ + idx4];
            s.x += x[b].x * m[b].x; s.y += x[b].y * m[b].y;
            s.z += x[b].z * m[b].z; s.w += x[b].w * m[b].w;
            c.x += m[b].x; c.y += m[b].y; c.z += m[b].z; c.w += m[b].w;
        }
        float4 pm;
        pm.x = s.x / (c.x + 1e-10f); pm.y = s.y / (c.y + 1e-10f);
        pm.z = s.z / (c.z + 1e-10f); pm.w = s.w / (c.w + 1e-10f);
#pragma unroll
        for (int b = 0; b < B_; b++) {
            size_t row = (size_t)b * D_ + d;
            ushort4 xm, mk;
            xm.x = f2bf(x[b].x * m[b].x + (1.f - m[b].x) * pm.x);
            xm.y = f2bf(x[b].y * m[b].y + (1.f - m[b].y) * pm.y);
            xm.z = f2bf(x[b].z * m[b].z + (1.f - m[b].z) * pm.z);
            xm.w = f2bf(x[b].w * m[b].w + (1.f - m[b].w) * pm.w);
            mk.x = f2bf(m[b].x); mk.y = f2bf(m[b].y);
            mk.z = f2bf(m[b].z); mk.w = f2bf(m[b].w);
            *(ushort4*)&Ain[row * KIN_ + t]      = xm;
            *(ushort4*)&Ain[row * KIN_ + T_ + t] = mk;
        }
    } else {
        int idx = (bx - 512) * 256 + threadIdx.x;
        if (idx < 64) rmaxkey[idx] = 0u;
        if (idx < 262144) {
            int n = idx >> 10, k = idx & 1023;     // Wt_in[n][k] = W_in[k][n]
            Wt_in[idx] = f2bf(W_in[(size_t)k * HID_ + n]);
        } else if (idx < 393216) {
            int j = idx - 262144;
            int l = j >> 16, n = (j >> 8) & 255, k = j & 255;
            int h = n >> 6, e = n & 63;
            Wcat[j] = f2bf(gatW[(((size_t)(l * NH_ + h) * HID_) + k) * OUT_ + e]);
        } else {
            int j = idx - 393216;
            int n = j >> 8, k = j & 255;           // WtO[n][k] = W_out[k][n]
            WtO[j] = f2bf(W_out[(size_t)k * T_ + n]);
        }
    }
}

// ---------------------------------------------------------------------------
// 2) bf16 MFMA GEMM. BM=64 BN=64 BK=64, 4 waves, wave = 16 rows x 64 cols.
//    Padded LDS (row stride 72) kills bank conflicts; reg-staged ping-pong.
//    MODE 0: fp32 C (+bias). MODE 1: + bf16 copy. MODE 2: hwT + s_l/s_r/rmax.
// ---------------------------------------------------------------------------
template <int MODE>
__global__ __launch_bounds__(256) void gemm_bf16_k(
        const unsigned short* __restrict__ A,    // M x K bf16
        const unsigned short* __restrict__ Bt,   // N x K bf16 (B transposed)
        const float* __restrict__ bias,          // N or null (MODE 0/1)
        float* __restrict__ C,                   // M x N fp32 (MODE 0/1)
        unsigned short* __restrict__ Cb,         // bf16 copy (MODE1) / hwT (MODE2)
        const float* __restrict__ ga,            // gat_a + l*512 (MODE2)
        float* __restrict__ s_l,                 // (MODE2)
        float* __restrict__ s_r,                 // (MODE2)
        unsigned int* __restrict__ rmaxkey,      // + l*32 (MODE2)
        int Nsz, int Ksz) {
    __shared__ __align__(16) unsigned short As[2][64 * 72];  // 18 KB, padded
    __shared__ __align__(16) unsigned short Bs[2][64 * 72];  // 18 KB
    int tid = threadIdx.x;
    int wave = tid >> 6, lane = tid & 63;
    int q = lane >> 4, r16 = lane & 15;
    int rowbase = blockIdx.y * 64;
    int colbase = blockIdx.x * 64;

    int srow = tid >> 3, sk = (tid & 7) * 8;         // staging slot
    const unsigned short* Ap0 = A + (size_t)(rowbase + srow) * Ksz + sk;
    const unsigned short* Ap1 = A + (size_t)(rowbase + srow + 32) * Ksz + sk;
    const unsigned short* Bp0 = Bt + (size_t)(colbase + srow) * Ksz + sk;
    const unsigned short* Bp1 = Bt + (size_t)(colbase + srow + 32) * Ksz + sk;
    int la0 = srow * 72 + sk, la1 = (srow + 32) * 72 + sk;

    floatx4 acc[4];
#pragma unroll
    for (int i = 0; i < 4; i++) acc[i] = (floatx4)0.f;

    uint4 pa0 = *(const uint4*)Ap0, pa1 = *(const uint4*)Ap1;
    uint4 pb0 = *(const uint4*)Bp0, pb1 = *(const uint4*)Bp1;
    *(uint4*)&As[0][la0] = pa0;
    *(uint4*)&As[0][la1] = pa1;
    *(uint4*)&Bs[0][la0] = pb0;
    *(uint4*)&Bs[0][la1] = pb1;

    int nk = Ksz >> 6;
    for (int it = 0; it < nk; it++) {
        int cur = it & 1;
        __syncthreads();
        if (it + 1 < nk) {
            int kt = (it + 1) << 6;
            pa0 = *(const uint4*)(Ap0 + kt);
            pa1 = *(const uint4*)(Ap1 + kt);
            pb0 = *(const uint4*)(Bp0 + kt);
            pb1 = *(const uint4*)(Bp1 + kt);
        }
#pragma unroll
        for (int t = 0; t < 2; t++) {
            short8 a = *(const short8*)&As[cur][(wave * 16 + r16) * 72 + t * 32 + q * 8];
#pragma unroll
            for (int ni = 0; ni < 4; ni++) {
                short8 b = *(const short8*)&Bs[cur][(ni * 16 + r16) * 72 + t * 32 + q * 8];
                acc[ni] = __builtin_amdgcn_mfma_f32_16x16x32_bf16(a, b, acc[ni], 0, 0, 0);
            }
        }
        if (it + 1 < nk) {
            int nxt = cur ^ 1;
            *(uint4*)&As[nxt][la0] = pa0;
            *(uint4*)&As[nxt][la1] = pa1;
            *(uint4*)&Bs[nxt][la0] = pb0;
            *(uint4*)&Bs[nxt][la1] = pb1;
        }
    }
    // ---- epilogue. C/D map: col=lane&15, row=(lane>>4)*4+reg ----
    if constexpr (MODE == 2) {
        int bhh = ((rowbase >> 10) << 2) + blockIdx.x;   // b*4 + h
        int nb = (rowbase & (D_ - 1)) + wave * 16;
        // hwT[bh][e][m] bf16
#pragma unroll
        for (int ni = 0; ni < 4; ni++) {
            int e = ni * 16 + r16;
            ushort4 pk;
            pk.x = f2bf(acc[ni][0]);
            pk.y = f2bf(acc[ni][1]);
            pk.z = f2bf(acc[ni][2]);
            pk.w = f2bf(acc[ni][3]);
            *(ushort4*)&Cb[((size_t)(bhh * 64 + e) << 10) + nb + q * 4] = pk;
        }
        // fused s_l/s_r from fp32 acc
        const float* gab = ga + blockIdx.x * 2 * OUT_;
        float al4[4], ar4[4];
#pragma unroll
        for (int ni = 0; ni < 4; ni++) {
            al4[ni] = gab[ni * 16 + r16];
            ar4[ni] = gab[OUT_ + ni * 16 + r16];
        }
        float slv[4], srv[4];
#pragma unroll
        for (int rr = 0; rr < 4; rr++) {
            float s1 = 0.f, s2 = 0.f;
#pragma unroll
            for (int ni = 0; ni < 4; ni++) {
                s1 += acc[ni][rr] * al4[ni];
                s2 += acc[ni][rr] * ar4[ni];
            }
            slv[rr] = s1;
            srv[rr] = s2;
        }
#pragma unroll
        for (int off = 1; off < 16; off <<= 1) {
#pragma unroll
            for (int rr = 0; rr < 4; rr++) {
                slv[rr] += __shfl_xor(slv[rr], off, 64);
                srv[rr] += __shfl_xor(srv[rr], off, 64);
            }
        }
        {
            int rsel = r16 & 3;
            float sv = (rsel == 0) ? slv[0] : (rsel == 1) ? slv[1] : (rsel == 2) ? slv[2] : slv[3];
            float rv = (rsel == 0) ? srv[0] : (rsel == 1) ? srv[1] : (rsel == 2) ? srv[2] : srv[3];
            int n = nb + q * 4 + rsel;
            if (r16 < 4)                 s_l[bhh * D_ + n] = sv;
            else if (r16 >= 8 && r16 < 12) s_r[bhh * D_ + n] = rv;
        }
        float mx = fmaxf(fmaxf(srv[0], srv[1]), fmaxf(srv[2], srv[3]));
        mx = fmaxf(mx, __shfl_xor(mx, 16, 64));
        mx = fmaxf(mx, __shfl_xor(mx, 32, 64));
        if (lane == 0) atomicMax(&rmaxkey[bhh], kenc(mx));
    } else {
#pragma unroll
        for (int rr = 0; rr < 4; rr++) {
            int row = rowbase + wave * 16 + q * 4 + rr;
#pragma unroll
            for (int ni = 0; ni < 4; ni++) {
                int col = colbase + ni * 16 + r16;
                float v = acc[ni][rr] + (bias ? bias[col] : 0.f);
                C[(size_t)row * Nsz + col] = v;
                if constexpr (MODE == 1) Cb[(size_t)row * Nsz + col] = f2bf(v);
            }
        }
    }
}

// ---------------------------------------------------------------------------
// 3) Attention via MFMA, split-m 2-way. grid (32 bh, 16 rowblocks, 2 halves),
//    256 thr, 4 waves; wave = 16 rows x half the m-range. Writes partial
//    acc (pacc) and denominator (pden); addln combines exactly.
// ---------------------------------------------------------------------------
__global__ __launch_bounds__(256) void attn_k(const unsigned short* __restrict__ hwT,
                                              const float* __restrict__ sl_g,
                                              const float* __restrict__ sr_g,
                                              const unsigned int* __restrict__ rmaxkey,
                                              float* __restrict__ pacc,
                                              float* __restrict__ pden) {
    int bh = blockIdx.x;
    int b = bh >> 2, h = bh & 3;
    int half = blockIdx.z;
    int mb = half * 512;
    int tid = threadIdx.x;
    int wave = tid >> 6, lane = tid & 63;
    int q = lane >> 4, r16 = lane & 15;

    __shared__ float srs[512];                                // 2 KB
    __shared__ __align__(16) unsigned short Vt[2][64][136];   // 34 KB ping-pong

    *(float2*)&srs[tid * 2] = *(const float2*)&sr_g[bh * D_ + mb + tid * 2];

    float rm = kdec(rmaxkey[bh]);
    int row0 = blockIdx.y * 64 + wave * 16;
    float sl = sl_g[bh * D_ + row0 + r16];
    float xm = sl + rm;
    float Mn = fmaxf(xm, ALPHA_ * xm);

    floatx4 acc[4];
#pragma unroll
    for (int i = 0; i < 4; i++) acc[i] = (floatx4)0.f;
    float dsum = 0.f;

    const unsigned short* vbase = hwT + ((size_t)(bh * 64) << 10) + mb;
    int se[4], sp[4];
#pragma unroll
    for (int i = 0; i < 4; i++) {
        int s = tid + i * 256;
        se[i] = s >> 4;
        sp[i] = (s & 15) * 8;
    }

    uint4 pre[4];
#pragma unroll
    for (int i = 0; i < 4; i++)
        pre[i] = *(const uint4*)&vbase[((size_t)se[i] << 10) + sp[i]];
#pragma unroll
    for (int i = 0; i < 4; i++)
        *(uint4*)&Vt[0][se[i]][sp[i]] = pre[i];
    __syncthreads();   // covers srs + buffer 0

    for (int c = 0; c < 4; c++) {
        int cur = c & 1;
        if (c < 3) {
            int mo = (c + 1) * 128;
#pragma unroll
            for (int i = 0; i < 4; i++)
                pre[i] = *(const uint4*)&vbase[((size_t)se[i] << 10) + mo + sp[i]];
        }
#pragma unroll
        for (int kk = 0; kk < 128; kk += 32) {
            int m0 = c * 128 + kk + q * 8;
            float4 s0 = *(const float4*)&srs[m0];
            float4 s1 = *(const float4*)&srs[m0 + 4];
            float sr8[8] = {s0.x, s0.y, s0.z, s0.w, s1.x, s1.y, s1.z, s1.w};
            float p[8];
#pragma unroll
            for (int j = 0; j < 8; j++) {
                float x = sl + sr8[j];
                float e = fmaxf(x, ALPHA_ * x);
                float pj = __expf(e - Mn);
                dsum += pj;
                p[j] = pj;
            }
            union { unsigned int u[4]; short8 s8; } cv;
#pragma unroll
            for (int j = 0; j < 4; j++) {
                unsigned int lo = (__float_as_uint(p[2 * j]) + 0x8000u) >> 16;
                unsigned int hi = (__float_as_uint(p[2 * j + 1]) + 0x8000u) & 0xffff0000u;
                cv.u[j] = hi | lo;
            }
#pragma unroll
            for (int ni = 0; ni < 4; ni++) {
                short8 bfr = *(const short8*)&Vt[cur][ni * 16 + r16][kk + q * 8];
                acc[ni] = __builtin_amdgcn_mfma_f32_16x16x32_bf16(cv.s8, bfr, acc[ni], 0, 0, 0);
            }
        }
        if (c < 3) {
#pragma unroll
            for (int i = 0; i < 4; i++)
                *(uint4*)&Vt[cur ^ 1][se[i]][sp[i]] = pre[i];
        }
        __syncthreads();
    }
    dsum += __shfl_xor(dsum, 16);
    dsum += __shfl_xor(dsum, 32);
    size_t gr0 = (size_t)b * D_ + row0;
    if (lane < 16) pden[((size_t)half * M_ + gr0 + r16) * NH_ + h] = dsum;
#pragma unroll
    for (int rr = 0; rr < 4; rr++) {
        int rloc = q * 4 + rr;
        size_t grow = gr0 + rloc;
#pragma unroll
        for (int ni = 0; ni < 4; ni++) {
            pacc[((size_t)half * M_ + grow) * HID_ + h * OUT_ + ni * 16 + r16] = acc[ni][rr];
        }
    }
}

// ---------------------------------------------------------------------------
// 4) h = LayerNorm(h + (pacc0+pacc1)/(pden0+pden1))*g + b; fp32 + bf16 out.
//    One wave per row, shfl-only reductions. grid 2048 x 256.
// ---------------------------------------------------------------------------
__global__ __launch_bounds__(256) void addln_k(float* __restrict__ h,
                                               const float* __restrict__ pacc,
                                               const float* __restrict__ pden,
                                               const float* __restrict__ g,
                                               const float* __restrict__ bb,
                                               unsigned short* __restrict__ hbf) {
    int wave = threadIdx.x >> 6, lane = threadIdx.x & 63;
    size_t row = (size_t)blockIdx.x * 4 + wave;
    float4 a  = *(const float4*)&h[row * HID_ + lane * 4];
    float4 p0 = *(const float4*)&pacc[row * HID_ + lane * 4];
    float4 p1 = *(const float4*)&pacc[((size_t)M_ + row) * HID_ + lane * 4];
    int hh = lane >> 4;
    float den = pden[row * NH_ + hh] + pden[((size_t)M_ + row) * NH_ + hh];
    float inv = 1.f / den;
    float4 v = {a.x + (p0.x + p1.x) * inv, a.y + (p0.y + p1.y) * inv,
                a.z + (p0.z + p1.z) * inv, a.w + (p0.w + p1.w) * inv};
    float s = v.x + v.y + v.z + v.w;
#pragma unroll
    for (int off = 1; off < 64; off <<= 1) s += __shfl_xor(s, off, 64);
    float mu = s * (1.f / HID_);
    float4 d = {v.x - mu, v.y - mu, v.z - mu, v.w - mu};
    float s2 = d.x * d.x + d.y * d.y + d.z * d.z + d.w * d.w;
#pragma unroll
    for (int off = 1; off < 64; off <<= 1) s2 += __shfl_xor(s2, off, 64);
    float rs = rsqrtf(s2 * (1.f / HID_) + EPS_);
    float4 gg = *(const float4*)&g[lane * 4];
    float4 bbv = *(const float4*)&bb[lane * 4];
    float4 res;
    res.x = d.x * rs * gg.x + bbv.x;
    res.y = d.y * rs * gg.y + bbv.y;
    res.z = d.z * rs * gg.z + bbv.z;
    res.w = d.w * rs * gg.w + bbv.w;
    *(float4*)&h[row * HID_ + lane * 4] = res;
    ushort4 pk = {f2bf(res.x), f2bf(res.y), f2bf(res.z), f2bf(res.w)};
    *(ushort4*)&hbf[row * HID_ + lane * 4] = pk;
}

// ---------------------------------------------------------------------------
extern "C" void kernel_launch(void* const* d_in, const int* in_sizes, int n_in,
                              void* d_out, int out_size, void* d_ws, size_t ws_size,
                              hipStream_t stream) {
    const float* X_obs = (const float*)d_in[0];
    const float* mask  = (const float*)d_in[1];
    const float* W_in  = (const float*)d_in[2];
    const float* b_in  = (const float*)d_in[3];
    const float* gat_W = (const float*)d_in[4];
    const float* gat_a = (const float*)d_in[5];
    const float* ln_g  = (const float*)d_in[6];
    const float* ln_b  = (const float*)d_in[7];
    const float* W_out = (const float*)d_in[8];
    const float* b_out = (const float*)d_in[9];
    float* out = (float*)d_out;

    // Workspace layout (~35 MB of the 256 MB d_ws):
    //  [0,16M):   Ain bf16 (M x 1024); dead after g1, then:
    //             hwT bf16 [32][64][1024] at [0,4M), pacc fp32 [2][M][256] at [4,20M)
    //  [20M,+):   pden fp32 [2][M][4] (256 KB)
    //  [21M,29M): hbuf fp32 (M x 256)
    //  [29M,33M): hbf bf16 (M x 256)
    //  [33M,+):   Wt_in, Wcat, WtO (bf16), slb/srb (fp32), rmaxkey (uint[64])
    char* base = (char*)d_ws;
    unsigned short* Ain  = (unsigned short*)base;
    unsigned short* hwT  = (unsigned short*)base;
    float* pacc = (float*)(base + (4u << 20));
    float* pden = (float*)(base + (20u << 20));
    float* hbuf = (float*)(base + (21u << 20));
    unsigned short* hbf   = (unsigned short*)(base + (29u << 20));
    unsigned short* Wt_in = (unsigned short*)(base + (33u << 20));
    unsigned short* Wcat  = Wt_in + (size_t)HID_ * KIN_;        // 256*1024
    unsigned short* WtO   = Wcat + (size_t)NL_ * HID_ * HID_;   // 2*256*256
    float* slb = (float*)(WtO + (size_t)T_ * HID_);             // 32*1024
    float* srb = slb + B_ * NH_ * D_;
    unsigned int* rmaxkey = (unsigned int*)(srb + B_ * NH_ * D_);  // [2][32]

    prep_k<<<2560, 256, 0, stream>>>(X_obs, mask, W_in, gat_W, W_out,
                                     Ain, Wt_in, Wcat, WtO, rmaxkey);

    // h = [X_mean|mask] @ W_in + b_in   (8192x1024)@(1024x256), fp32+bf16 out
    gemm_bf16_k<1><<<dim3(HID_ / 64, M_ / 64), 256, 0, stream>>>(
        Ain, Wt_in, b_in, hbuf, hbf, nullptr, nullptr, nullptr, nullptr,
        HID_, KIN_);

    for (int l = 0; l < NL_; l++) {
        // hW = h @ Wcat[l] -> hwT bf16 + fused s_l/s_r/rmax
        gemm_bf16_k<2><<<dim3(HID_ / 64, M_ / 64), 256, 0, stream>>>(
            hbf, Wcat + (size_t)l * HID_ * HID_, nullptr, nullptr, hwT,
            gat_a + (size_t)l * NH_ * 2 * OUT_, slb, srb, rmaxkey + l * 32,
            HID_, HID_);
        attn_k<<<dim3(B_ * NH_, D_ / 64, 2), 256, 0, stream>>>(
            hwT, slb, srb, rmaxkey + l * 32, pacc, pden);
        addln_k<<<M_ / 4, 256, 0, stream>>>(hbuf, pacc, pden,
                                            ln_g + (size_t)l * HID_,
                                            ln_b + (size_t)l * HID_, hbf);
    }

    // out = h @ W_out + b_out  (8192x256)@(256x512), fp32 out
    gemm_bf16_k<0><<<dim3(T_ / 64, M_ / 64), 256, 0, stream>>>(
        hbf, WtO, b_out, out, nullptr, nullptr, nullptr, nullptr, nullptr,
        T_, HID_);
}